// Round 17
// baseline (433.089 us; speedup 1.0000x reference)
//
#include <hip/hip_runtime.h>

#define TT 2048
#define BB 512
#define HH 64
#define HIST 64
#define HISTP 65   // odd padded stride -> conflict-free row & column access

typedef unsigned uint2v __attribute__((ext_vector_type(2)));

// DPP mov: value of v from lane (lane ^ mask) — XOR patterns only (direction-
// unambiguous). All ctrl codes below validated on HW by round-15's passing run.
#define DPPM(v, ctrl) \
    __int_as_float(__builtin_amdgcn_update_dpp(0, __float_as_int(v), (ctrl), 0xF, 0xF, false))

// POLARITY-INDEPENDENT partner fetch across lane^16 / lane^32 (validated R15):
// r = permlane_swap(v,v) returns {even-dup, odd-dup} in some order; sum is
// order-independent; partner = sum - own.
__device__ __forceinline__ float recv16(float v) {
#if __has_builtin(__builtin_amdgcn_permlane16_swap)
    uint2v r = __builtin_amdgcn_permlane16_swap(__float_as_uint(v), __float_as_uint(v), false, false);
    return (__uint_as_float(r[0]) + __uint_as_float(r[1])) - v;
#else
    float a = v, b = v;
    asm volatile("s_nop 1\n\tv_permlane16_swap_b32 %0, %1" : "+v"(a), "+v"(b));
    return (a + b) - v;
#endif
}
__device__ __forceinline__ float recv32(float v) {
#if __has_builtin(__builtin_amdgcn_permlane32_swap)
    uint2v r = __builtin_amdgcn_permlane32_swap(__float_as_uint(v), __float_as_uint(v), false, false);
    return (__uint_as_float(r[0]) + __uint_as_float(r[1])) - v;
#else
    float a = v, b = v;
    asm volatile("s_nop 1\n\tv_permlane32_swap_b32 %0, %1" : "+v"(a), "+v"(b));
    return (a + b) - v;
#endif
}

// One wave per block. Recurrence is 100% register/cross-lane: lane L holds h_L;
// 15 XOR-DPP movs gather the row's 16 values; 64 scalar FMAs form partials for
// 4 outputs; 2-stage permlane reduce-scatter lands output d at lane d.
// No LDS and no barrier on the recurrence path (LDS write->read turnaround
// ~240 cyc was the R12/R16 floor). LDS hist ring is for y only.
__global__ __launch_bounds__(64, 1) void rnn_fused(
    const float* __restrict__ x,     // [T][B]
    const float* __restrict__ h0,    // [B][H]
    const float* __restrict__ Wih,   // [H]
    const float* __restrict__ Whh,   // [H][H]
    const float* __restrict__ bih,   // [H]
    const float* __restrict__ bhh,   // [H]
    const float* __restrict__ Wlin,  // [H]
    const float* __restrict__ blin,  // [1]
    float* __restrict__ y,           // [T][B]
    float* __restrict__ hN)          // [B][H]
{
    __shared__ float wsh[HH * HH];        // W_hh staging for the setup gather
    __shared__ float xsh[TT + 4];         // x column (+pad for t+1 probe)
    __shared__ float hist[HH][HISTP];     // wlin-premultiplied h, transposed

    const int b    = blockIdx.x;    // batch column
    const int lane = threadIdx.x;   // 0..63 == hidden index owned by this lane
    const int rb   = lane & 15;     // in-row index
    const int R    = lane >> 4;     // DPP row == K-slice index

    // ---- Prologue (single wave, in-order DS pipe: no barriers) ----
    for (int i = lane; i < HH * HH; i += 64) wsh[i] = Whh[i];
    for (int i = lane; i < TT; i += 64)      xsh[i] = x[(size_t)i * BB + b];
    if (lane < 4) xsh[TT + lane] = 0.f;

    const float KSC = 2.885390081777927f;  // 2/ln2 pre-scale (tanh via exp2)

    // w[a][m] pairs with rotation r[m] = h_{16R + (rb^m)}:
    // w[a][m] = W[16a+rb][16R + (rb^m)] * KSC
    float w[4][16];
#pragma unroll
    for (int a = 0; a < 4; ++a)
#pragma unroll
        for (int m = 0; m < 16; ++m)
            w[a][m] = wsh[(16 * a + rb) * HH + 16 * R + (rb ^ m)] * KSC;

    const float wihs  = Wih[lane] * KSC;
    const float biass = (bih[lane] + bhh[lane]) * KSC;
    const float wlinL = Wlin[lane];
    const float bl    = blin[0];

    const bool L4 = (lane & 16) != 0;
    const bool L5 = (lane & 32) != 0;

    float hval = h0[(size_t)b * HH + lane];   // h_lane lives in lane forever
    float xw   = fmaf(xsh[0], wihs, biass);   // x-projection for step 0

    // ---- Recurrence ----
#pragma unroll 1
    for (int tc = 0; tc < TT; tc += HIST) {
#pragma unroll 2
        for (int ti = 0; ti < HIST; ++ti) {
            const int t = tc + ti;

            // 15-mov XOR-DPP tree: r[m] = h value of lane^m (row-local)
            float r[16];
            r[0]  = hval;
            r[1]  = DPPM(hval,  0xB1);   // xor1
            r[2]  = DPPM(hval,  0x4E);   // xor2
            r[3]  = DPPM(r[2],  0xB1);   // xor3
            r[7]  = DPPM(hval,  0x141);  // xor7 (row_half_mirror)
            r[6]  = DPPM(r[7],  0xB1);
            r[5]  = DPPM(r[7],  0x4E);
            r[4]  = DPPM(r[5],  0xB1);
            r[15] = DPPM(hval,  0x140);  // xor15 (row_mirror)
            r[14] = DPPM(r[15], 0xB1);
            r[13] = DPPM(r[15], 0x4E);
            r[12] = DPPM(r[13], 0xB1);
            r[8]  = DPPM(r[15], 0x141);  // xor8
            r[9]  = DPPM(r[8],  0xB1);
            r[10] = DPPM(r[8],  0x4E);
            r[11] = DPPM(r[10], 0xB1);

            // partials for outputs d = 16a + rb over my K-slice (2 chains each)
            float p0, p1, p2, p3;
            {
                float e0 = 0.f, e1 = 0.f;
#pragma unroll
                for (int m = 0; m < 16; m += 2) {
                    e0 = fmaf(r[m],     w[0][m],     e0);
                    e1 = fmaf(r[m + 1], w[0][m + 1], e1);
                }
                p0 = e0 + e1;
            }
            {
                float e0 = 0.f, e1 = 0.f;
#pragma unroll
                for (int m = 0; m < 16; m += 2) {
                    e0 = fmaf(r[m],     w[1][m],     e0);
                    e1 = fmaf(r[m + 1], w[1][m + 1], e1);
                }
                p1 = e0 + e1;
            }
            {
                float e0 = 0.f, e1 = 0.f;
#pragma unroll
                for (int m = 0; m < 16; m += 2) {
                    e0 = fmaf(r[m],     w[2][m],     e0);
                    e1 = fmaf(r[m + 1], w[2][m + 1], e1);
                }
                p2 = e0 + e1;
            }
            {
                float e0 = 0.f, e1 = 0.f;
#pragma unroll
                for (int m = 0; m < 16; m += 2) {
                    e0 = fmaf(r[m],     w[3][m],     e0);
                    e1 = fmaf(r[m + 1], w[3][m + 1], e1);
                }
                p3 = e0 + e1;
            }

            // stage 1 (lane^16): keep a0==L4 partials, fetch partner's same
            const float keep0 = L4 ? p1 : p0;
            const float send0 = L4 ? p0 : p1;
            const float keep1 = L4 ? p3 : p2;
            const float send1 = L4 ? p2 : p3;
            const float q0 = keep0 + recv16(send0);
            const float q1 = keep1 + recv16(send1);

            // stage 2 (lane^32): keep a1==L5
            const float keep = L5 ? q1 : q0;
            const float send = L5 ? q0 : q1;
            const float acc  = keep + recv32(send) + xw;  // lands at lane d==L

            // tanh = 1 - 2/(2^{acc}+1)   (pre-scaled by 2/ln2)
            const float e2 = __builtin_amdgcn_exp2f(acc);
            const float rr = __builtin_amdgcn_rcpf(e2 + 1.0f);
            hval = fmaf(-2.0f, rr, 1.0f);

            // y ring: premultiplied by wlin; (lane*65+ti)%32 distinct -> free
            hist[lane][ti] = hval * wlinL;

            // next-step x projection (uniform broadcast read, off-chain)
            xw = fmaf(xsh[t + 1], wihs, biass);
        }

        // ---- bulk y: lane -> t = tc + lane; column sum, conflict-free ----
        {
            float acc = bl;
#pragma unroll
            for (int d2 = 0; d2 < HH; ++d2)
                acc += hist[d2][lane];
            y[(size_t)(tc + lane) * BB + b] = acc;
        }
        // same wave: next chunk's ring writes are ordered after these reads
    }

    // ---- Epilogue ----
    hN[(size_t)b * HH + lane] = hval;
}

extern "C" void kernel_launch(void* const* d_in, const int* in_sizes, int n_in,
                              void* d_out, int out_size, void* d_ws, size_t ws_size,
                              hipStream_t stream) {
    const float* x    = (const float*)d_in[0];
    const float* h0   = (const float*)d_in[1];
    const float* Wih  = (const float*)d_in[2];
    const float* Whh  = (const float*)d_in[3];
    const float* bih  = (const float*)d_in[4];
    const float* bhh  = (const float*)d_in[5];
    const float* Wlin = (const float*)d_in[6];
    const float* blin = (const float*)d_in[7];

    float* y  = (float*)d_out;            // [T*B]
    float* hN = (float*)d_out + TT * BB;  // [B*H]

    rnn_fused<<<dim3(BB), dim3(64), 0, stream>>>(x, h0, Wih, Whh, bih, bhh, Wlin, blin, y, hN);
}